// Round 1
// baseline (370.461 us; speedup 1.0000x reference)
//
#include <hip/hip_runtime.h>
#include <cstddef>

// Shapes: B=8, NWIN=256, NTOK=64, DIM=192, HEADS=6, d=32, 3C=576
// ws layout (u16 units from base):
//   vT16    [0,        25165824)  bf16 v transposed [(b*192+ch)][win*64+tok]
//   attbuf  [25165824, 50331648)  bf16 softmax@V output [(b*192+ch)][i*64+tok]
//   qg,kg   f32 at u16 offset 50331648 (2 x 393216 f32)
//   Wh [576][192] bf16, Wl [384][192] bf16 (qkv weight hi/lo), Wp [192][192] bf16

#define SCALE 0.17677669529663687f   // 1/sqrt(32)

typedef __attribute__((ext_vector_type(8))) short short8;
typedef __attribute__((ext_vector_type(4))) float f32x4;

__device__ __forceinline__ unsigned short f2bf(float f) {
    unsigned u = __float_as_uint(f);
    u += 0x7fffu + ((u >> 16) & 1u);
    return (unsigned short)(u >> 16);
}
__device__ __forceinline__ float bf2f(unsigned int h) {
    return __uint_as_float(h << 16);
}
__device__ __forceinline__ unsigned pack2(unsigned short a, unsigned short b) {
    return (unsigned)a | ((unsigned)b << 16);
}

// ---------------- qkv weights -> bf16 hi (all 576 rows) + lo (first 384 rows) ----------------
__global__ __launch_bounds__(256) void wsplit_kernel(
    const float* __restrict__ w, unsigned short* __restrict__ Wh,
    unsigned short* __restrict__ Wl)
{
    int idx = blockIdx.x * 256 + threadIdx.x;   // < 110592 = 576*192
    float v = w[idx];
    unsigned short h = f2bf(v);
    Wh[idx] = h;
    if (idx < 73728) Wl[idx] = f2bf(v - bf2f(h));   // rows 0..383 (q,k)
}

// ---------------- proj weights -> bf16 ----------------
__global__ __launch_bounds__(256) void wproj_kernel(
    const float* __restrict__ w, unsigned short* __restrict__ Wp)
{
    int idx = blockIdx.x * 256 + threadIdx.x;   // < 36864
    Wp[idx] = f2bf(w[idx]);
}

// ---------------- Kernel A: fused split + N-resident QKV GEMM + grad epilogue ----------------
// v2: Bs staging removed (weights streamed L2->regs directly: 368 KB shared by all
// blocks, LDS broadcast was pure overhead + 8.2M bank-conflict cycles + forced
// 1 block/CU). As kept in LDS (hi/lo split computed once per element) but in
// MFMA-fragment tile order [tile16][kpart][col][8] -> ds_read_b128/ds_write_b128
// are lane-linear (conflict-free, no padding). Double-buffered (32 KB total),
// one barrier per chunk. launch_bounds(512,2) -> 2 blocks/CU resident.
__global__ __launch_bounds__(512, 2) void qkv_fused_kernel(
    const float* __restrict__ x, const unsigned short* __restrict__ Wh,
    const unsigned short* __restrict__ Wl, const float* __restrict__ bias,
    unsigned short* __restrict__ vT, float* __restrict__ qg, float* __restrict__ kg)
{
    // [2 buf][8 tiles][4 kpart][16 col][8 u16] = 2*4096 u16 each
    __shared__ unsigned short As_h[2 * 128 * 32];
    __shared__ unsigned short As_l[2 * 128 * 32];

    const int tid = threadIdx.x;
    const int wave = tid >> 6, lane = tid & 63;
    const int quad = lane >> 4, col = lane & 15;
    const int wq = wave & 3;
    const int wofs4 = (wave >> 2) * 4;      // row-tile base (tiles of 16 rows)
    const int m0 = blockIdx.x * 128;

    // staging assignment: thread -> (row = tid>>2, kpart = tid&3 of 8 floats)
    const int arow = tid >> 2;              // 0..127
    const int apart = tid & 3;              // 0..3
    const float* xp = x + (size_t)(m0 + arow) * 192 + apart * 8;
    // tiled LDS slot (u16 units): tile = arow>>4, slot = kpart*16 + (arow&15)
    const int aslot = (((arow >> 4) * 64) + apart * 16 + (arow & 15)) * 8;

    // B fragment base: row (wq + s*4)*16 + col, k offset quad*8; s stride = 64 rows
    const unsigned short* wh_base = Wh + (size_t)(wq * 16 + col) * 192 + quad * 8;
    const unsigned short* wl_base = Wl + (size_t)(wq * 16 + col) * 192 + quad * 8;

    f32x4 acc[9][4];
#pragma unroll
    for (int s = 0; s < 9; ++s)
#pragma unroll
        for (int mi = 0; mi < 4; ++mi) {
            f32x4 z = {0.f, 0.f, 0.f, 0.f};
            acc[s][mi] = z;
        }

    float4 pa0, pa1;
    auto load_chunk = [&](int kk) {
        pa0 = *(const float4*)(xp + kk * 32);
        pa1 = *(const float4*)(xp + kk * 32 + 4);
    };
    auto write_chunk = [&](int nb) {
        float v[8] = {pa0.x, pa0.y, pa0.z, pa0.w, pa1.x, pa1.y, pa1.z, pa1.w};
        unsigned short h[8], l[8];
#pragma unroll
        for (int i = 0; i < 8; ++i) {
            h[i] = f2bf(v[i]);
            l[i] = f2bf(v[i] - bf2f(h[i]));
        }
        uint4 H = make_uint4(pack2(h[0], h[1]), pack2(h[2], h[3]),
                             pack2(h[4], h[5]), pack2(h[6], h[7]));
        uint4 L = make_uint4(pack2(l[0], l[1]), pack2(l[2], l[3]),
                             pack2(l[4], l[5]), pack2(l[6], l[7]));
        *(uint4*)&As_h[nb * 4096 + aslot] = H;
        *(uint4*)&As_l[nb * 4096 + aslot] = L;
    };

    // per-mi fragment read offsets (lane-linear within each tile)
    int ro8[4];
#pragma unroll
    for (int mi = 0; mi < 4; ++mi)
        ro8[mi] = ((wofs4 + mi) * 64 + quad * 16 + col) * 8;

    load_chunk(0);
    write_chunk(0);
    __syncthreads();

    for (int kk = 0; kk < 6; ++kk) {
        const int cur = kk & 1;
        if (kk < 5) load_chunk(kk + 1);       // x prefetch (HBM/L3, used at bottom)

        const int kw = kk * 32;
        uint4 pbh[9], pbl[6];
#pragma unroll
        for (int s = 0; s < 9; ++s)
            pbh[s] = *(const uint4*)(wh_base + s * 12288 + kw);
#pragma unroll
        for (int s = 0; s < 6; ++s)
            pbl[s] = *(const uint4*)(wl_base + s * 12288 + kw);

        short8 ah[4], al[4];
#pragma unroll
        for (int mi = 0; mi < 4; ++mi) {
            ah[mi] = *(const short8*)&As_h[cur * 4096 + ro8[mi]];
            al[mi] = *(const short8*)&As_l[cur * 4096 + ro8[mi]];
        }

#pragma unroll
        for (int s = 0; s < 9; ++s) {
            short8 bh = *(const short8*)&pbh[s];
            if (s < 6) {
                short8 bl = *(const short8*)&pbl[s];
#pragma unroll
                for (int mi = 0; mi < 4; ++mi) {
                    acc[s][mi] = __builtin_amdgcn_mfma_f32_16x16x32_bf16(al[mi], bh, acc[s][mi], 0, 0, 0);
                    acc[s][mi] = __builtin_amdgcn_mfma_f32_16x16x32_bf16(ah[mi], bl, acc[s][mi], 0, 0, 0);
                    acc[s][mi] = __builtin_amdgcn_mfma_f32_16x16x32_bf16(ah[mi], bh, acc[s][mi], 0, 0, 0);
                }
            } else {
#pragma unroll
                for (int mi = 0; mi < 4; ++mi)
                    acc[s][mi] = __builtin_amdgcn_mfma_f32_16x16x32_bf16(ah[mi], bh, acc[s][mi], 0, 0, 0);
            }
        }

        if (kk < 5) write_chunk(1 - cur);     // convert+stage next chunk (other buffer)
        __syncthreads();
    }

    // bias (before grads: zero-pad boundary terms keep the bias)
#pragma unroll
    for (int s = 0; s < 9; ++s) {
        float bv = bias[(wq + s * 4) * 16 + col];
#pragma unroll
        for (int mi = 0; mi < 4; ++mi)
#pragma unroll
            for (int r = 0; r < 4; ++r)
                acc[s][mi][r] += bv;
    }

    const int gw = blockIdx.x * 2 + (wave >> 2);     // global window of this wave
    const int b = gw >> 8, win = gw & 255;

    // s = 0..2 -> q (ntiles 0..11), 3..5 -> k (12..23), 6..8 -> v (24..35)
#pragma unroll
    for (int s = 0; s < 6; ++s) {
        const int n = wq + s * 4;
        float yx[4][4], p3[4];
#pragma unroll
        for (int mi = 0; mi < 4; ++mi) {
#pragma unroll
            for (int r = 0; r < 4; ++r)
                yx[mi][r] = __shfl_xor(acc[s][mi][r], 32);
            p3[mi] = __shfl_xor(acc[s][mi][3], 16);
        }
        float sum = 0.f;
#pragma unroll
        for (int mi = 0; mi < 4; ++mi)
#pragma unroll
            for (int r = 0; r < 4; ++r) {
                float v = acc[s][mi][r];
                float gx = (r > 0) ? (v - acc[s][mi][r - 1])
                                   : ((quad & 1) ? (v - p3[mi]) : v);
                float gy = (quad >= 2) ? (v - yx[mi][r])
                                       : ((mi > 0) ? (v - yx[mi - 1][r]) : v);
                sum += fabsf(gx) + fabsf(gy);
            }
        sum += __shfl_xor(sum, 16);
        sum += __shfl_xor(sum, 32);
        float* dst = (s < 3) ? qg : kg;
        const int chb = ((s < 3) ? n : n - 12) * 16;
        const float sc = (s < 3) ? SCALE : 1.0f;
        if (lane < 16)
            dst[(size_t)(b * 192 + chb + lane) * 256 + win] = sum * sc;
    }
#pragma unroll
    for (int s = 6; s < 9; ++s) {
        const int ch = (wq + s * 4 - 24) * 16 + col;
#pragma unroll
        for (int mi = 0; mi < 4; ++mi) {
            int tok0 = mi * 16 + quad * 4;
            ushort4 o = make_ushort4(f2bf(acc[s][mi][0]), f2bf(acc[s][mi][1]),
                                     f2bf(acc[s][mi][2]), f2bf(acc[s][mi][3]));
            *(ushort4*)(vT + (size_t)(b * 192 + ch) * 16384 + win * 64 + tok0) = o;
        }
    }
}

// ---------------- Kernel B: MFMA rank-1-score softmax attention ----------------
// grid 1536 (one block per (b,ch)), 256 threads = 4 waves; wave w owns query
// windows i in [w*64, w*64+64). C = E[256x256] @ V[256x64], E built in-register.
__global__ __launch_bounds__(256) void attn_mfma_kernel(
    const unsigned short* __restrict__ vT, const float* __restrict__ qg,
    const float* __restrict__ kg, unsigned short* __restrict__ attbuf)
{
    __shared__ unsigned short Vs[64 * 264];   // [tok 64][j 256], stride 264
    __shared__ float kds[256];
    __shared__ float red[256];

    const int g = blockIdx.x;
    const int tid = threadIdx.x;
    const int wave = tid >> 6, lane = tid & 63;
    const int quad = lane >> 4, col = lane & 15;

    float kv = kg[(size_t)g * 256 + tid];
    red[tid] = kv;
    __syncthreads();
    for (int s = 128; s > 0; s >>= 1) {
        if (tid < s) red[tid] = fmaxf(red[tid], red[tid + s]);
        __syncthreads();
    }
    kds[tid] = kv - red[0];                    // <= 0

    // stage V transposed: Vs[tok][j] <- vT[g][j*64+tok]
    const unsigned short* vb = vT + (size_t)g * 16384;
    {
        const int jr = tid >> 3;               // 0..31
        const int tb = (tid & 7) * 8;          // tok base
#pragma unroll
        for (int it = 0; it < 8; ++it) {
            int j = it * 32 + jr;
            uint4 u = *(const uint4*)(vb + (size_t)j * 64 + tb);
            Vs[(tb + 0) * 264 + j] = (unsigned short)(u.x & 0xffffu);
            Vs[(tb + 1) * 264 + j] = (unsigned short)(u.x >> 16);
            Vs[(tb + 2) * 264 + j] = (unsigned short)(u.y & 0xffffu);
            Vs[(tb + 3) * 264 + j] = (unsigned short)(u.y >> 16);
            Vs[(tb + 4) * 264 + j] = (unsigned short)(u.z & 0xffffu);
            Vs[(tb + 5) * 264 + j] = (unsigned short)(u.z >> 16);
            Vs[(tb + 6) * 264 + j] = (unsigned short)(u.w & 0xffffu);
            Vs[(tb + 7) * 264 + j] = (unsigned short)(u.w >> 16);
        }
    }

    float ai[4];
#pragma unroll
    for (int mi = 0; mi < 4; ++mi)
        ai[mi] = qg[(size_t)g * 256 + wave * 64 + mi * 16 + col];

    __syncthreads();

    f32x4 acc[4][4];
#pragma unroll
    for (int mi = 0; mi < 4; ++mi)
#pragma unroll
        for (int ni = 0; ni < 4; ++ni) {
            f32x4 z = {0.f, 0.f, 0.f, 0.f};
            acc[mi][ni] = z;
        }
    float den[4] = {0.f, 0.f, 0.f, 0.f};

    for (int kt = 0; kt < 8; ++kt) {
        const int k0 = kt * 32;
        float4 ka = *(const float4*)&kds[k0 + quad * 8];
        float4 kb = *(const float4*)&kds[k0 + quad * 8 + 4];
        float kv8[8] = {ka.x, ka.y, ka.z, ka.w, kb.x, kb.y, kb.z, kb.w};

        short8 bfr[4];
#pragma unroll
        for (int ni = 0; ni < 4; ++ni)
            bfr[ni] = *(const short8*)&Vs[(ni * 16 + col) * 264 + k0 + quad * 8];

#pragma unroll
        for (int mi = 0; mi < 4; ++mi) {
            short8 ef;
            float dl = 0.f;
#pragma unroll
            for (int j = 0; j < 8; ++j) {
                float e = __expf(ai[mi] * kv8[j]);
                unsigned short h = f2bf(e);
                ef[j] = (short)h;
                dl += bf2f(h);
            }
            den[mi] += dl;
#pragma unroll
            for (int ni = 0; ni < 4; ++ni)
                acc[mi][ni] = __builtin_amdgcn_mfma_f32_16x16x32_bf16(
                    ef, bfr[ni], acc[mi][ni], 0, 0, 0);
        }
    }

#pragma unroll
    for (int mi = 0; mi < 4; ++mi) {
        den[mi] += __shfl_xor(den[mi], 16);
        den[mi] += __shfl_xor(den[mi], 32);
    }

    unsigned short* ob = attbuf + (size_t)g * 16384;
#pragma unroll
    for (int mi = 0; mi < 4; ++mi) {
        float invr[4];
#pragma unroll
        for (int r = 0; r < 4; ++r)
            invr[r] = 1.0f / __shfl(den[mi], quad * 4 + r);
#pragma unroll
        for (int ni = 0; ni < 4; ++ni)
#pragma unroll
            for (int r = 0; r < 4; ++r) {
                int i = wave * 64 + mi * 16 + quad * 4 + r;
                int tok = ni * 16 + col;
                ob[i * 64 + tok] = f2bf(acc[mi][ni][r] * invr[r]);
            }
    }
}

// ---------------- Kernel C: MFMA proj GEMM (C^T = Wp . attbuf^T) ----------------
__global__ __launch_bounds__(256) void proj_mfma_kernel(
    const unsigned short* __restrict__ attbuf, const unsigned short* __restrict__ Wp,
    const float* __restrict__ bias, float* __restrict__ out)
{
    __shared__ unsigned short Bs[64 * 40];    // [row 64][ch 32], stride 40
    __shared__ float T[32 * 197];             // transpose half-buffer

    const int tid = threadIdx.x;
    const int wave = tid >> 6, lane = tid & 63;
    const int quad = lane >> 4, col = lane & 15;
    const int rowg0 = blockIdx.x * 64;
    const int b = rowg0 >> 14;
    const int rl0 = rowg0 & 16383;
    const unsigned short* ab = attbuf + (size_t)b * 3145728;

    f32x4 acc[3][4];
#pragma unroll
    for (int mi = 0; mi < 3; ++mi)
#pragma unroll
        for (int ni = 0; ni < 4; ++ni) {
            f32x4 z = {0.f, 0.f, 0.f, 0.f};
            acc[mi][ni] = z;
        }

    const int chl = tid >> 3;            // 0..31
    const int rb = (tid & 7) * 8;        // row base

    for (int kt = 0; kt < 6; ++kt) {
        __syncthreads();
        {
            uint4 u = *(const uint4*)(ab + (size_t)(kt * 32 + chl) * 16384 + rl0 + rb);
            Bs[(rb + 0) * 40 + chl] = (unsigned short)(u.x & 0xffffu);
            Bs[(rb + 1) * 40 + chl] = (unsigned short)(u.x >> 16);
            Bs[(rb + 2) * 40 + chl] = (unsigned short)(u.y & 0xffffu);
            Bs[(rb + 3) * 40 + chl] = (unsigned short)(u.y >> 16);
            Bs[(rb + 4) * 40 + chl] = (unsigned short)(u.z & 0xffffu);
            Bs[(rb + 5) * 40 + chl] = (unsigned short)(u.z >> 16);
            Bs[(rb + 6) * 40 + chl] = (unsigned short)(u.w & 0xffffu);
            Bs[(rb + 7) * 40 + chl] = (unsigned short)(u.w >> 16);
        }
        __syncthreads();

        short8 bfr[4], af[3];
#pragma unroll
        for (int ni = 0; ni < 4; ++ni)
            bfr[ni] = *(const short8*)&Bs[(ni * 16 + col) * 40 + quad * 8];
#pragma unroll
        for (int mi = 0; mi < 3; ++mi)
            af[mi] = *(const short8*)(Wp + (size_t)(wave * 48 + mi * 16 + col) * 192
                                      + kt * 32 + quad * 8);
#pragma unroll
        for (int mi = 0; mi < 3; ++mi)
#pragma unroll
            for (int ni = 0; ni < 4; ++ni)
                acc[mi][ni] = __builtin_amdgcn_mfma_f32_16x16x32_bf16(
                    af[mi], bfr[ni], acc[mi][ni], 0, 0, 0);
    }

    float br[3][4];
#pragma unroll
    for (int mi = 0; mi < 3; ++mi)
#pragma unroll
        for (int r = 0; r < 4; ++r)
            br[mi][r] = bias[wave * 48 + mi * 16 + quad * 4 + r];

#pragma unroll
    for (int h = 0; h < 2; ++h) {
        __syncthreads();
#pragma unroll
        for (int nh = 0; nh < 2; ++nh) {
            int ni = h * 2 + nh;
#pragma unroll
            for (int mi = 0; mi < 3; ++mi)
#pragma unroll
                for (int r = 0; r < 4; ++r)
                    T[(nh * 16 + col) * 197 + wave * 48 + mi * 16 + quad * 4 + r] =
                        acc[mi][ni][r] + br[mi][r];
        }
        __syncthreads();
        {
            int row = tid >> 3;              // 0..31
            int ck = (tid & 7) * 24;         // cout chunk
            float* op = out + (size_t)(rowg0 + h * 32 + row) * 192 + ck;
#pragma unroll
            for (int q4 = 0; q4 < 6; ++q4) {
                float4 o = make_float4(T[row * 197 + ck + q4 * 4 + 0],
                                       T[row * 197 + ck + q4 * 4 + 1],
                                       T[row * 197 + ck + q4 * 4 + 2],
                                       T[row * 197 + ck + q4 * 4 + 3]);
                *(float4*)(op + q4 * 4) = o;
            }
        }
    }
}

extern "C" void kernel_launch(void* const* d_in, const int* in_sizes, int n_in,
                              void* d_out, int out_size, void* d_ws, size_t ws_size,
                              hipStream_t stream) {
    const float* x      = (const float*)d_in[0];
    const float* qkv_w  = (const float*)d_in[1];
    const float* qkv_b  = (const float*)d_in[2];
    const float* proj_w = (const float*)d_in[3];
    const float* proj_b = (const float*)d_in[4];
    float* out = (float*)d_out;

    unsigned short* base16 = (unsigned short*)d_ws;
    unsigned short* vT16   = base16;                      // 25165824 u16
    unsigned short* attbuf = base16 + 25165824;           // 25165824 u16
    float* qg = (float*)(base16 + 50331648);              // 393216 f32
    float* kg = qg + 393216;                              // 393216 f32
    unsigned short* Wh = (unsigned short*)(kg + 393216);  // 110592 u16
    unsigned short* Wl = Wh + 110592;                     // 73728 u16
    unsigned short* Wp = Wl + 73728;                      // 36864 u16

    wsplit_kernel<<<432, 256, 0, stream>>>(qkv_w, Wh, Wl);
    wproj_kernel<<<144, 256, 0, stream>>>(proj_w, Wp);
    qkv_fused_kernel<<<1024, 512, 0, stream>>>(x, Wh, Wl, qkv_b, vT16, qg, kg);
    attn_mfma_kernel<<<1536, 256, 0, stream>>>(vT16, qg, kg, attbuf);
    proj_mfma_kernel<<<2048, 256, 0, stream>>>(attbuf, Wp, proj_b, out);
}

// Round 3
// 351.014 us; speedup vs baseline: 1.0554x; 1.0554x over previous
//
#include <hip/hip_runtime.h>
#include <cstddef>

// Shapes: B=8, NWIN=256, NTOK=64, DIM=192, HEADS=6, d=32, 3C=576
// ws layout (u16 units from base):
//   vT16    [0,        25165824)  bf16 v transposed [(b*192+ch)][win*64+tok]
//   attbuf  [25165824, 50331648)  bf16 softmax@V output [(b*192+ch)][i*64+tok]
//   qg,kg   f32 at u16 offset 50331648 (2 x 393216 f32)
//   Wh [576][192] bf16, Wl [384][192] bf16 (qkv weight hi/lo), Wp [192][192] bf16

#define SCALE 0.17677669529663687f   // 1/sqrt(32)

typedef __attribute__((ext_vector_type(8))) short short8;
typedef __attribute__((ext_vector_type(4))) float f32x4;

__device__ __forceinline__ unsigned short f2bf(float f) {
    unsigned u = __float_as_uint(f);
    u += 0x7fffu + ((u >> 16) & 1u);
    return (unsigned short)(u >> 16);
}
__device__ __forceinline__ float bf2f(unsigned int h) {
    return __uint_as_float(h << 16);
}
__device__ __forceinline__ unsigned pack2(unsigned short a, unsigned short b) {
    return (unsigned)a | ((unsigned)b << 16);
}

// ---------------- qkv weights -> bf16 hi (all 576 rows) + lo (first 384 rows) ----------------
__global__ __launch_bounds__(256) void wsplit_kernel(
    const float* __restrict__ w, unsigned short* __restrict__ Wh,
    unsigned short* __restrict__ Wl)
{
    int idx = blockIdx.x * 256 + threadIdx.x;   // < 110592 = 576*192
    float v = w[idx];
    unsigned short h = f2bf(v);
    Wh[idx] = h;
    if (idx < 73728) Wl[idx] = f2bf(v - bf2f(h));   // rows 0..383 (q,k)
}

// ---------------- proj weights -> bf16 ----------------
__global__ __launch_bounds__(256) void wproj_kernel(
    const float* __restrict__ w, unsigned short* __restrict__ Wp)
{
    int idx = blockIdx.x * 256 + threadIdx.x;   // < 36864
    Wp[idx] = f2bf(w[idx]);
}

// ---------------- Kernel A: fused split + QKV GEMM + grad epilogue ----------------
// v3 (resubmit; round-2 bench failed on container infra, no kernel signal).
// Register-pressure fix vs v2: x hi/lo staged ONCE to LDS for full K=192
// (48 KB, MFMA-fragment-tiled, lane-linear = conflict-free), then the 9 n-tiles
// are processed in 3 groups of 3 with a K-loop each: only acc[3][4] (48 regs)
// + double-buffered W frags + A frags live -> ~140 regs. Block = 256 thr
// (1 window, 4 col-waves); LDS 48 KB -> 3 blocks = 12 waves/CU.
__global__ __launch_bounds__(256, 3) void qkv_fused_kernel(
    const float* __restrict__ x, const unsigned short* __restrict__ Wh,
    const unsigned short* __restrict__ Wl, const float* __restrict__ bias,
    unsigned short* __restrict__ vT, float* __restrict__ qg, float* __restrict__ kg)
{
    // [kk 6][mi 4][kpart 4][col 16][8 u16] ; frag read addr = kk*2048+mi*512+lane*8
    __shared__ unsigned short As_h[6 * 2048];
    __shared__ unsigned short As_l[6 * 2048];

    const int tid = threadIdx.x;
    const int wq = tid >> 6, lane = tid & 63;
    const int quad = lane >> 4, col = lane & 15;
    const int gw = blockIdx.x;                 // global window
    const int b = gw >> 8, win = gw & 255;
    const int m0 = gw * 64;

    // ---- prologue: stage x -> LDS hi/lo, full K ----
    {
        const int arow = tid >> 2;             // 0..63
        const int apart = tid & 3;             // 0..3 (8 floats each)
        const float* xp = x + (size_t)(m0 + arow) * 192 + apart * 8;
        const int slot = (arow >> 4) * 512 + apart * 128 + (arow & 15) * 8;
        float4 va[6], vb[6];
#pragma unroll
        for (int kk = 0; kk < 6; ++kk) {
            va[kk] = *(const float4*)(xp + kk * 32);
            vb[kk] = *(const float4*)(xp + kk * 32 + 4);
        }
#pragma unroll
        for (int kk = 0; kk < 6; ++kk) {
            float v[8] = {va[kk].x, va[kk].y, va[kk].z, va[kk].w,
                          vb[kk].x, vb[kk].y, vb[kk].z, vb[kk].w};
            unsigned short h[8], l[8];
#pragma unroll
            for (int i = 0; i < 8; ++i) {
                h[i] = f2bf(v[i]);
                l[i] = f2bf(v[i] - bf2f(h[i]));
            }
            uint4 H = make_uint4(pack2(h[0], h[1]), pack2(h[2], h[3]),
                                 pack2(h[4], h[5]), pack2(h[6], h[7]));
            uint4 L = make_uint4(pack2(l[0], l[1]), pack2(l[2], l[3]),
                                 pack2(l[4], l[5]), pack2(l[6], l[7]));
            *(uint4*)&As_h[kk * 2048 + slot] = H;
            *(uint4*)&As_l[kk * 2048 + slot] = L;
        }
    }
    __syncthreads();

    // B fragment base: row (wq + s*4)*16 + col, k offset quad*8; s stride 12288 u16
    const unsigned short* wh_base = Wh + (size_t)(wq * 16 + col) * 192 + quad * 8;
    const unsigned short* wl_base = Wl + (size_t)(wq * 16 + col) * 192 + quad * 8;

#pragma unroll
    for (int g = 0; g < 3; ++g) {              // g=0: q, g=1: k, g=2: v
        const bool qk = (g < 2);

        f32x4 acc[3][4];
#pragma unroll
        for (int js = 0; js < 3; ++js)
#pragma unroll
            for (int mi = 0; mi < 4; ++mi) {
                f32x4 z = {0.f, 0.f, 0.f, 0.f};
                acc[js][mi] = z;
            }

        uint4 cbh[3], cbl[3], nbh[3], nbl[3];
#pragma unroll
        for (int js = 0; js < 3; ++js) {
            const int s = g * 3 + js;
            cbh[js] = *(const uint4*)(wh_base + (size_t)s * 12288);
            if (qk) cbl[js] = *(const uint4*)(wl_base + (size_t)s * 12288);
        }

#pragma unroll
        for (int kk = 0; kk < 6; ++kk) {
            if (kk < 5) {
#pragma unroll
                for (int js = 0; js < 3; ++js) {
                    const int s = g * 3 + js;
                    nbh[js] = *(const uint4*)(wh_base + (size_t)s * 12288 + (kk + 1) * 32);
                    if (qk) nbl[js] = *(const uint4*)(wl_base + (size_t)s * 12288 + (kk + 1) * 32);
                }
            }
            short8 ah[4], al[4];
#pragma unroll
            for (int mi = 0; mi < 4; ++mi) {
                ah[mi] = *(const short8*)&As_h[kk * 2048 + mi * 512 + lane * 8];
                if (qk) al[mi] = *(const short8*)&As_l[kk * 2048 + mi * 512 + lane * 8];
            }
#pragma unroll
            for (int js = 0; js < 3; ++js) {
                short8 bh = *(const short8*)&cbh[js];
                if (qk) {
                    short8 bl = *(const short8*)&cbl[js];
#pragma unroll
                    for (int mi = 0; mi < 4; ++mi) {
                        acc[js][mi] = __builtin_amdgcn_mfma_f32_16x16x32_bf16(al[mi], bh, acc[js][mi], 0, 0, 0);
                        acc[js][mi] = __builtin_amdgcn_mfma_f32_16x16x32_bf16(ah[mi], bl, acc[js][mi], 0, 0, 0);
                        acc[js][mi] = __builtin_amdgcn_mfma_f32_16x16x32_bf16(ah[mi], bh, acc[js][mi], 0, 0, 0);
                    }
                } else {
#pragma unroll
                    for (int mi = 0; mi < 4; ++mi)
                        acc[js][mi] = __builtin_amdgcn_mfma_f32_16x16x32_bf16(ah[mi], bh, acc[js][mi], 0, 0, 0);
                }
            }
#pragma unroll
            for (int js = 0; js < 3; ++js) {
                cbh[js] = nbh[js];
                if (qk) cbl[js] = nbl[js];
            }
        }

        // ---- group epilogue (acc still live, only 12 tiles) ----
        if (g < 2) {
            // q (g=0) / k (g=1): bias, grad magnitude, store to qg/kg
#pragma unroll
            for (int js = 0; js < 3; ++js) {
                const int s = g * 3 + js;
                const int n = wq + s * 4;
                const float bv = bias[n * 16 + col];
#pragma unroll
                for (int mi = 0; mi < 4; ++mi)
#pragma unroll
                    for (int r = 0; r < 4; ++r)
                        acc[js][mi][r] += bv;

                float yx[4][4], p3[4];
#pragma unroll
                for (int mi = 0; mi < 4; ++mi) {
#pragma unroll
                    for (int r = 0; r < 4; ++r)
                        yx[mi][r] = __shfl_xor(acc[js][mi][r], 32);
                    p3[mi] = __shfl_xor(acc[js][mi][3], 16);
                }
                float sum = 0.f;
#pragma unroll
                for (int mi = 0; mi < 4; ++mi)
#pragma unroll
                    for (int r = 0; r < 4; ++r) {
                        float v = acc[js][mi][r];
                        float gx = (r > 0) ? (v - acc[js][mi][r - 1])
                                           : ((quad & 1) ? (v - p3[mi]) : v);
                        float gy = (quad >= 2) ? (v - yx[mi][r])
                                               : ((mi > 0) ? (v - yx[mi - 1][r]) : v);
                        sum += fabsf(gx) + fabsf(gy);
                    }
                sum += __shfl_xor(sum, 16);
                sum += __shfl_xor(sum, 32);
                float* dst = (g == 0) ? qg : kg;
                const int chb = ((g == 0) ? n : n - 12) * 16;
                const float sc = (g == 0) ? SCALE : 1.0f;
                if (lane < 16)
                    dst[(size_t)(b * 192 + chb + lane) * 256 + win] = sum * sc;
            }
        } else {
            // v: bias + bf16 store to vT
#pragma unroll
            for (int js = 0; js < 3; ++js) {
                const int s = 6 + js;
                const int n = wq + s * 4;
                const float bv = bias[n * 16 + col];
                const int ch = (n - 24) * 16 + col;
#pragma unroll
                for (int mi = 0; mi < 4; ++mi) {
                    int tok0 = mi * 16 + quad * 4;
                    ushort4 o = make_ushort4(f2bf(acc[js][mi][0] + bv),
                                             f2bf(acc[js][mi][1] + bv),
                                             f2bf(acc[js][mi][2] + bv),
                                             f2bf(acc[js][mi][3] + bv));
                    *(ushort4*)(vT + (size_t)(b * 192 + ch) * 16384 + win * 64 + tok0) = o;
                }
            }
        }
    }
}

// ---------------- Kernel B: MFMA rank-1-score softmax attention ----------------
// grid 1536 (one block per (b,ch)), 256 threads = 4 waves; wave w owns query
// windows i in [w*64, w*64+64). C = E[256x256] @ V[256x64], E built in-register.
__global__ __launch_bounds__(256) void attn_mfma_kernel(
    const unsigned short* __restrict__ vT, const float* __restrict__ qg,
    const float* __restrict__ kg, unsigned short* __restrict__ attbuf)
{
    __shared__ unsigned short Vs[64 * 264];   // [tok 64][j 256], stride 264
    __shared__ float kds[256];
    __shared__ float red[256];

    const int g = blockIdx.x;
    const int tid = threadIdx.x;
    const int wave = tid >> 6, lane = tid & 63;
    const int quad = lane >> 4, col = lane & 15;

    float kv = kg[(size_t)g * 256 + tid];
    red[tid] = kv;
    __syncthreads();
    for (int s = 128; s > 0; s >>= 1) {
        if (tid < s) red[tid] = fmaxf(red[tid], red[tid + s]);
        __syncthreads();
    }
    kds[tid] = kv - red[0];                    // <= 0

    // stage V transposed: Vs[tok][j] <- vT[g][j*64+tok]
    const unsigned short* vb = vT + (size_t)g * 16384;
    {
        const int jr = tid >> 3;               // 0..31
        const int tb = (tid & 7) * 8;          // tok base
#pragma unroll
        for (int it = 0; it < 8; ++it) {
            int j = it * 32 + jr;
            uint4 u = *(const uint4*)(vb + (size_t)j * 64 + tb);
            Vs[(tb + 0) * 264 + j] = (unsigned short)(u.x & 0xffffu);
            Vs[(tb + 1) * 264 + j] = (unsigned short)(u.x >> 16);
            Vs[(tb + 2) * 264 + j] = (unsigned short)(u.y & 0xffffu);
            Vs[(tb + 3) * 264 + j] = (unsigned short)(u.y >> 16);
            Vs[(tb + 4) * 264 + j] = (unsigned short)(u.z & 0xffffu);
            Vs[(tb + 5) * 264 + j] = (unsigned short)(u.z >> 16);
            Vs[(tb + 6) * 264 + j] = (unsigned short)(u.w & 0xffffu);
            Vs[(tb + 7) * 264 + j] = (unsigned short)(u.w >> 16);
        }
    }

    float ai[4];
#pragma unroll
    for (int mi = 0; mi < 4; ++mi)
        ai[mi] = qg[(size_t)g * 256 + wave * 64 + mi * 16 + col];

    __syncthreads();

    f32x4 acc[4][4];
#pragma unroll
    for (int mi = 0; mi < 4; ++mi)
#pragma unroll
        for (int ni = 0; ni < 4; ++ni) {
            f32x4 z = {0.f, 0.f, 0.f, 0.f};
            acc[mi][ni] = z;
        }
    float den[4] = {0.f, 0.f, 0.f, 0.f};

    for (int kt = 0; kt < 8; ++kt) {
        const int k0 = kt * 32;
        float4 ka = *(const float4*)&kds[k0 + quad * 8];
        float4 kb = *(const float4*)&kds[k0 + quad * 8 + 4];
        float kv8[8] = {ka.x, ka.y, ka.z, ka.w, kb.x, kb.y, kb.z, kb.w};

        short8 bfr[4];
#pragma unroll
        for (int ni = 0; ni < 4; ++ni)
            bfr[ni] = *(const short8*)&Vs[(ni * 16 + col) * 264 + k0 + quad * 8];

#pragma unroll
        for (int mi = 0; mi < 4; ++mi) {
            short8 ef;
            float dl = 0.f;
#pragma unroll
            for (int j = 0; j < 8; ++j) {
                float e = __expf(ai[mi] * kv8[j]);
                unsigned short h = f2bf(e);
                ef[j] = (short)h;
                dl += bf2f(h);
            }
            den[mi] += dl;
#pragma unroll
            for (int ni = 0; ni < 4; ++ni)
                acc[mi][ni] = __builtin_amdgcn_mfma_f32_16x16x32_bf16(
                    ef, bfr[ni], acc[mi][ni], 0, 0, 0);
        }
    }

#pragma unroll
    for (int mi = 0; mi < 4; ++mi) {
        den[mi] += __shfl_xor(den[mi], 16);
        den[mi] += __shfl_xor(den[mi], 32);
    }

    unsigned short* ob = attbuf + (size_t)g * 16384;
#pragma unroll
    for (int mi = 0; mi < 4; ++mi) {
        float invr[4];
#pragma unroll
        for (int r = 0; r < 4; ++r)
            invr[r] = 1.0f / __shfl(den[mi], quad * 4 + r);
#pragma unroll
        for (int ni = 0; ni < 4; ++ni)
#pragma unroll
            for (int r = 0; r < 4; ++r) {
                int i = wave * 64 + mi * 16 + quad * 4 + r;
                int tok = ni * 16 + col;
                ob[i * 64 + tok] = f2bf(acc[mi][ni][r] * invr[r]);
            }
    }
}

// ---------------- Kernel C: MFMA proj GEMM (C^T = Wp . attbuf^T) ----------------
__global__ __launch_bounds__(256) void proj_mfma_kernel(
    const unsigned short* __restrict__ attbuf, const unsigned short* __restrict__ Wp,
    const float* __restrict__ bias, float* __restrict__ out)
{
    __shared__ unsigned short Bs[64 * 40];    // [row 64][ch 32], stride 40
    __shared__ float T[32 * 197];             // transpose half-buffer

    const int tid = threadIdx.x;
    const int wave = tid >> 6, lane = tid & 63;
    const int quad = lane >> 4, col = lane & 15;
    const int rowg0 = blockIdx.x * 64;
    const int b = rowg0 >> 14;
    const int rl0 = rowg0 & 16383;
    const unsigned short* ab = attbuf + (size_t)b * 3145728;

    f32x4 acc[3][4];
#pragma unroll
    for (int mi = 0; mi < 3; ++mi)
#pragma unroll
        for (int ni = 0; ni < 4; ++ni) {
            f32x4 z = {0.f, 0.f, 0.f, 0.f};
            acc[mi][ni] = z;
        }

    const int chl = tid >> 3;            // 0..31
    const int rb = (tid & 7) * 8;        // row base

    for (int kt = 0; kt < 6; ++kt) {
        __syncthreads();
        {
            uint4 u = *(const uint4*)(ab + (size_t)(kt * 32 + chl) * 16384 + rl0 + rb);
            Bs[(rb + 0) * 40 + chl] = (unsigned short)(u.x & 0xffffu);
            Bs[(rb + 1) * 40 + chl] = (unsigned short)(u.x >> 16);
            Bs[(rb + 2) * 40 + chl] = (unsigned short)(u.y & 0xffffu);
            Bs[(rb + 3) * 40 + chl] = (unsigned short)(u.y >> 16);
            Bs[(rb + 4) * 40 + chl] = (unsigned short)(u.z & 0xffffu);
            Bs[(rb + 5) * 40 + chl] = (unsigned short)(u.z >> 16);
            Bs[(rb + 6) * 40 + chl] = (unsigned short)(u.w & 0xffffu);
            Bs[(rb + 7) * 40 + chl] = (unsigned short)(u.w >> 16);
        }
        __syncthreads();

        short8 bfr[4], af[3];
#pragma unroll
        for (int ni = 0; ni < 4; ++ni)
            bfr[ni] = *(const short8*)&Bs[(ni * 16 + col) * 40 + quad * 8];
#pragma unroll
        for (int mi = 0; mi < 3; ++mi)
            af[mi] = *(const short8*)(Wp + (size_t)(wave * 48 + mi * 16 + col) * 192
                                      + kt * 32 + quad * 8);
#pragma unroll
        for (int mi = 0; mi < 3; ++mi)
#pragma unroll
            for (int ni = 0; ni < 4; ++ni)
                acc[mi][ni] = __builtin_amdgcn_mfma_f32_16x16x32_bf16(
                    af[mi], bfr[ni], acc[mi][ni], 0, 0, 0);
    }

    float br[3][4];
#pragma unroll
    for (int mi = 0; mi < 3; ++mi)
#pragma unroll
        for (int r = 0; r < 4; ++r)
            br[mi][r] = bias[wave * 48 + mi * 16 + quad * 4 + r];

#pragma unroll
    for (int h = 0; h < 2; ++h) {
        __syncthreads();
#pragma unroll
        for (int nh = 0; nh < 2; ++nh) {
            int ni = h * 2 + nh;
#pragma unroll
            for (int mi = 0; mi < 3; ++mi)
#pragma unroll
                for (int r = 0; r < 4; ++r)
                    T[(nh * 16 + col) * 197 + wave * 48 + mi * 16 + quad * 4 + r] =
                        acc[mi][ni][r] + br[mi][r];
        }
        __syncthreads();
        {
            int row = tid >> 3;              // 0..31
            int ck = (tid & 7) * 24;         // cout chunk
            float* op = out + (size_t)(rowg0 + h * 32 + row) * 192 + ck;
#pragma unroll
            for (int q4 = 0; q4 < 6; ++q4) {
                float4 o = make_float4(T[row * 197 + ck + q4 * 4 + 0],
                                       T[row * 197 + ck + q4 * 4 + 1],
                                       T[row * 197 + ck + q4 * 4 + 2],
                                       T[row * 197 + ck + q4 * 4 + 3]);
                *(float4*)(op + q4 * 4) = o;
            }
        }
    }
}

extern "C" void kernel_launch(void* const* d_in, const int* in_sizes, int n_in,
                              void* d_out, int out_size, void* d_ws, size_t ws_size,
                              hipStream_t stream) {
    const float* x      = (const float*)d_in[0];
    const float* qkv_w  = (const float*)d_in[1];
    const float* qkv_b  = (const float*)d_in[2];
    const float* proj_w = (const float*)d_in[3];
    const float* proj_b = (const float*)d_in[4];
    float* out = (float*)d_out;

    unsigned short* base16 = (unsigned short*)d_ws;
    unsigned short* vT16   = base16;                      // 25165824 u16
    unsigned short* attbuf = base16 + 25165824;           // 25165824 u16
    float* qg = (float*)(base16 + 50331648);              // 393216 f32
    float* kg = qg + 393216;                              // 393216 f32
    unsigned short* Wh = (unsigned short*)(kg + 393216);  // 110592 u16
    unsigned short* Wl = Wh + 110592;                     // 73728 u16
    unsigned short* Wp = Wl + 73728;                      // 36864 u16

    wsplit_kernel<<<432, 256, 0, stream>>>(qkv_w, Wh, Wl);
    wproj_kernel<<<144, 256, 0, stream>>>(proj_w, Wp);
    qkv_fused_kernel<<<2048, 256, 0, stream>>>(x, Wh, Wl, qkv_b, vT16, qg, kg);
    attn_mfma_kernel<<<1536, 256, 0, stream>>>(vT16, qg, kg, attbuf);
    proj_mfma_kernel<<<2048, 256, 0, stream>>>(attbuf, Wp, proj_b, out);
}